// Round 1
// baseline (1179.696 us; speedup 1.0000x reference)
//
#include <hip/hip_runtime.h>

#define RR 12
#define PD 25
#define PP 625
#define HH 30
#define WW 30
#define HWD 900
#define CD 512
#define BD 8
#define TD 4

// relu + L2-normalize over channel dim; output [plane][pixel][c] (c-contiguous)
__global__ __launch_bounds__(256) void norm_kernel(const float* __restrict__ in,
                                                   float* __restrict__ out,
                                                   int c_stride, int t_count) {
    int tile = blockIdx.x;
    int plane = blockIdx.y;
    int b = plane / t_count;
    int t = plane - b * t_count;
    long base = (long)b * CD * c_stride + (long)t * HWD;  // c_stride = t_count*HWD
    int hw0 = tile * 32;
    int nvalid = min(32, HWD - hw0);
    __shared__ float tilebuf[32][516];
    __shared__ float inv[32];
    int tid = threadIdx.x;
    // load + relu + transpose into LDS: 64 iters * 256 thr = 512*32 elems
    for (int it = 0; it < 64; ++it) {
        int lin = it * 256 + tid;
        int c = lin >> 5;
        int p = lin & 31;
        float v = 0.f;
        if (p < nvalid) v = in[base + (long)c * c_stride + hw0 + p];
        tilebuf[p][c] = fmaxf(v, 0.f);
    }
    __syncthreads();
    // sum of squares: 8 threads per pixel, float4 strided
    {
        int p = tid >> 3, s8 = tid & 7;
        float acc = 0.f;
#pragma unroll
        for (int j = 0; j < 16; ++j) {
            const float4 v = *reinterpret_cast<const float4*>(&tilebuf[p][(s8 + j * 8) * 4]);
            acc += v.x * v.x + v.y * v.y + v.z * v.z + v.w * v.w;
        }
        acc += __shfl_xor(acc, 1);
        acc += __shfl_xor(acc, 2);
        acc += __shfl_xor(acc, 4);
        if (s8 == 0) inv[p] = 1.0f / fmaxf(sqrtf(acc), 1e-12f);
    }
    __syncthreads();
    // write normalized, coalesced: out[(plane*HW + hw0+p)*C + c]
    for (int it = 0; it < 64; ++it) {
        int lin = it * 256 + tid;
        int p = lin >> 9;
        int c = lin & 511;
        if (p < nvalid)
            out[((long)plane * HWD + hw0 + p) * CD + c] = tilebuf[p][c] * inv[p];
    }
}

// one block per (b,t,h): 625 correlations x 30 pixels, fused softmax + mask
__global__ __launch_bounds__(256) void corr_softmax_kernel(
    const float* __restrict__ Qn, const float* __restrict__ Vn,
    float* __restrict__ out) {
    int h = blockIdx.x;   // 0..29
    int bt = blockIdx.y;  // 0..31
    int b = bt >> 2;
    __shared__ float corr[30 * 640];
    __shared__ float m_lds[30];
    __shared__ float is_lds[30];
    int tid = threadIdx.x;
    int wave = tid >> 6, lane = tid & 63;
    int g = lane >> 4, k = lane & 15;

    for (int i = tid; i < 30 * 640; i += 256) corr[i] = 0.f;

    int wA = wave * 8 + g;
    int wB = wave * 8 + 4 + g;
    bool vA = wA < WW, vB = wB < WW;
    const float* qbase = Qn + ((long)b * HWD + h * WW) * CD;
    float4 qa[8], qb[8];
    {
        const float* pa = qbase + (long)(vA ? wA : 0) * CD + k * 4;
        const float* pb = qbase + (long)(vB ? wB : 0) * CD + k * 4;
#pragma unroll
        for (int j = 0; j < 8; ++j) {
            qa[j] = *reinterpret_cast<const float4*>(pa + j * 64);
            qb[j] = *reinterpret_cast<const float4*>(pb + j * 64);
        }
    }
    __syncthreads();  // corr zeroed

    const float* vbase = Vn + (long)bt * HWD * CD;
    for (int dh = 0; dh < PD; ++dh) {
        int y = h + dh - RR;
        if ((unsigned)y >= (unsigned)HH) continue;  // corr stays 0 (zero padding)
        const float* vrow = vbase + (long)(y * WW) * CD;
        for (int x = 0; x < WW; ++x) {
            float4 v[8];
            const float* pv = vrow + (long)x * CD + k * 4;
#pragma unroll
            for (int j = 0; j < 8; ++j)
                v[j] = *reinterpret_cast<const float4*>(pv + j * 64);
            int dwA = x - wA + RR;
            if (vA && (unsigned)dwA < (unsigned)PD) {
                float d = 0.f;
#pragma unroll
                for (int j = 0; j < 8; ++j)
                    d += qa[j].x * v[j].x + qa[j].y * v[j].y + qa[j].z * v[j].z + qa[j].w * v[j].w;
                d += __shfl_xor(d, 1);
                d += __shfl_xor(d, 2);
                d += __shfl_xor(d, 4);
                d += __shfl_xor(d, 8);
                if (k == 0) corr[wA * 640 + dh * PD + dwA] = d;
            }
            int dwB = x - wB + RR;
            if (vB && (unsigned)dwB < (unsigned)PD) {
                float d = 0.f;
#pragma unroll
                for (int j = 0; j < 8; ++j)
                    d += qb[j].x * v[j].x + qb[j].y * v[j].y + qb[j].z * v[j].z + qb[j].w * v[j].w;
                d += __shfl_xor(d, 1);
                d += __shfl_xor(d, 2);
                d += __shfl_xor(d, 4);
                d += __shfl_xor(d, 8);
                if (k == 0) corr[wB * 640 + dh * PD + dwB] = d;
            }
        }
    }
    __syncthreads();
    // per-pixel softmax stats over 625 offsets (incl. zeros for OOB offsets)
    for (int w = wave; w < WW; w += 4) {
        float m = 0.f;  // all entries >= 0, zeros present
        for (int i = lane; i < PP; i += 64) m = fmaxf(m, corr[w * 640 + i]);
        m = fmaxf(m, __shfl_xor(m, 1));
        m = fmaxf(m, __shfl_xor(m, 2));
        m = fmaxf(m, __shfl_xor(m, 4));
        m = fmaxf(m, __shfl_xor(m, 8));
        m = fmaxf(m, __shfl_xor(m, 16));
        m = fmaxf(m, __shfl_xor(m, 32));
        float s = 0.f;
        for (int i = lane; i < PP; i += 64) s += __expf(512.f * (corr[w * 640 + i] - m));
        s += __shfl_xor(s, 1);
        s += __shfl_xor(s, 2);
        s += __shfl_xor(s, 4);
        s += __shfl_xor(s, 8);
        s += __shfl_xor(s, 16);
        s += __shfl_xor(s, 32);
        if (lane == 0) {
            m_lds[w] = m;
            is_lds[w] = 1.0f / s;
        }
    }
    __syncthreads();
    // masked write: out[bt][i=dh*25+dw][h][w]
    float* obase = out + (long)bt * PP * HWD + h * WW;
    for (int idx = tid; idx < PP * WW; idx += 256) {
        int i = idx / 30;
        int w = idx - i * 30;
        int dh = i / 25, dw = i - dh * 25;
        bool valid = ((unsigned)(h + dh - RR) < (unsigned)HH) &&
                     ((unsigned)(w + dw - RR) < (unsigned)WW);
        float val = -1.0f;
        if (valid) val = __expf(512.f * (corr[w * 640 + i] - m_lds[w])) * is_lds[w];
        obase[(long)i * HWD + w] = val;
    }
}

extern "C" void kernel_launch(void* const* d_in, const int* in_sizes, int n_in,
                              void* d_out, int out_size, void* d_ws, size_t ws_size,
                              hipStream_t stream) {
    const float* feat1 = (const float*)d_in[0];  // video [8,512,4,30,30]
    const float* feat2 = (const float*)d_in[1];  // patch [8,512,30,30]
    float* out = (float*)d_out;
    float* Qn = (float*)d_ws;                       // [8][900][512]
    float* Vn = Qn + (size_t)BD * HWD * CD;         // [32][900][512]

    // patch: 8 planes, channel stride 900
    norm_kernel<<<dim3(29, 8), 256, 0, stream>>>(feat2, Qn, HWD, 1);
    // video: 32 planes (b*4+t), channel stride 3600
    norm_kernel<<<dim3(29, 32), 256, 0, stream>>>(feat1, Vn, TD * HWD, TD);
    corr_softmax_kernel<<<dim3(30, 32), 256, 0, stream>>>(Qn, Vn, out);
}

// Round 2
// 447.788 us; speedup vs baseline: 2.6345x; 2.6345x over previous
//
#include <hip/hip_runtime.h>

#define RR 12
#define PD 25
#define PP 625
#define HH 30
#define WW 30
#define HWD 900
#define CD 512
#define BD 8
#define TD 4
#define CSTRIDE 628  // 625 + 3 pad, bank-friendly

typedef __attribute__((ext_vector_type(8))) short bf16x8;
typedef __attribute__((ext_vector_type(4))) float f32x4;

__device__ __forceinline__ unsigned short f2bf_rn(float x) {
    unsigned int u = __float_as_uint(x);
    u += 0x7fffu + ((u >> 16) & 1u);
    return (unsigned short)(u >> 16);
}

// relu + L2-normalize over channel dim; emit hi/lo split bf16, [plane][pixel][c]
__global__ __launch_bounds__(256) void norm_kernel(const float* __restrict__ in,
                                                   unsigned short* __restrict__ outH,
                                                   unsigned short* __restrict__ outL,
                                                   int c_stride, int t_count) {
    int tile = blockIdx.x;
    int plane = blockIdx.y;
    int b = plane / t_count;
    int t = plane - b * t_count;
    long base = (long)b * CD * c_stride + (long)t * HWD;
    int hw0 = tile * 32;
    int nvalid = min(32, HWD - hw0);
    __shared__ float tilebuf[32][516];
    __shared__ float inv[32];
    int tid = threadIdx.x;
    for (int it = 0; it < 64; ++it) {
        int lin = it * 256 + tid;
        int c = lin >> 5;
        int p = lin & 31;
        float v = 0.f;
        if (p < nvalid) v = in[base + (long)c * c_stride + hw0 + p];
        tilebuf[p][c] = fmaxf(v, 0.f);
    }
    __syncthreads();
    {
        int p = tid >> 3, s8 = tid & 7;
        float acc = 0.f;
#pragma unroll
        for (int j = 0; j < 16; ++j) {
            const float4 v = *reinterpret_cast<const float4*>(&tilebuf[p][(s8 + j * 8) * 4]);
            acc += v.x * v.x + v.y * v.y + v.z * v.z + v.w * v.w;
        }
        acc += __shfl_xor(acc, 1);
        acc += __shfl_xor(acc, 2);
        acc += __shfl_xor(acc, 4);
        if (s8 == 0) inv[p] = 1.0f / fmaxf(sqrtf(acc), 1e-12f);
    }
    __syncthreads();
    for (int it = 0; it < 64; ++it) {
        int lin = it * 256 + tid;
        int p = lin >> 9;
        int c = lin & 511;
        if (p < nvalid) {
            float nv = tilebuf[p][c] * inv[p];
            unsigned short hs = f2bf_rn(nv);
            float hf = __uint_as_float((unsigned int)hs << 16);
            float lo = nv - hf;
            size_t idx = ((size_t)plane * HWD + hw0 + p) * CD + c;
            outH[idx] = hs;
            outL[idx] = f2bf_rn(lo);
        }
    }
}

// block = (h, bt); 4 waves = (mt in {0,1}) x (y-half in {0,1})
// S[w][y][x] via 16x16x32 bf16 MFMA, 3-pass split; fused softmax + masked write
__global__ __launch_bounds__(256, 2) void corr_kernel(
    const unsigned short* __restrict__ Qh, const unsigned short* __restrict__ Ql,
    const unsigned short* __restrict__ Vh, const unsigned short* __restrict__ Vl,
    float* __restrict__ out) {
    int h = blockIdx.x;   // 0..29
    int bt = blockIdx.y;  // 0..31
    int b = bt >> 2;
    __shared__ float corr[HH * CSTRIDE];
    __shared__ float m_lds[HH];
    __shared__ float is_lds[HH];
    int tid = threadIdx.x;
    int wid = tid >> 6, lane = tid & 63;
    int mt = wid & 1, yh = wid >> 1;

    for (int i = tid; i < HH * CSTRIDE; i += 256) corr[i] = 0.f;

    // ---- A fragments (Q rows for this M-tile) held in registers, full K ----
    int arow = lane & 15;   // A row within tile
    int kg = lane >> 4;     // k-group (8 contiguous k per lane)
    int wa = mt * 16 + arow;
    int wac = min(wa, 29);  // clamp pad rows (guarded out at store)
    const unsigned short* qb = Qh + ((size_t)(b * HWD + h * WW + wac)) * CD + kg * 8;
    const unsigned short* qbL = Ql + ((size_t)(b * HWD + h * WW + wac)) * CD + kg * 8;
    bf16x8 aH[16], aL[16];
#pragma unroll
    for (int ks = 0; ks < 16; ++ks) {
        aH[ks] = *(const bf16x8*)(qb + ks * 32);
        aL[ks] = *(const bf16x8*)(qbL + ks * 32);
    }
    __syncthreads();  // corr zeroed

    int x0 = lane & 15;          // N-tile 0 column (always < 16, valid)
    int x1c = min(x0 + 16, 29);  // N-tile 1 column, clamped (guarded at store)
    int xo0 = lane & 15, xo1 = xo0 + 16;
    const size_t vplane = (size_t)bt * HWD * CD;

    int dhs = yh * 13;
    int dhe = yh ? 25 : 13;
    for (int dh = dhs; dh < dhe; ++dh) {
        int y = h + dh - RR;
        if ((unsigned)y >= (unsigned)HH) continue;  // corr row stays 0 (zero-pad)
        const unsigned short* vr = Vh + vplane + (size_t)(y * WW) * CD + kg * 8;
        const unsigned short* vrL = Vl + vplane + (size_t)(y * WW) * CD + kg * 8;
        const unsigned short* p0 = vr + (size_t)x0 * CD;
        const unsigned short* p0L = vrL + (size_t)x0 * CD;
        const unsigned short* p1 = vr + (size_t)x1c * CD;
        const unsigned short* p1L = vrL + (size_t)x1c * CD;

        f32x4 acc0a = {0, 0, 0, 0}, acc0b = {0, 0, 0, 0}, acc0c = {0, 0, 0, 0};
        f32x4 acc1a = {0, 0, 0, 0}, acc1b = {0, 0, 0, 0}, acc1c = {0, 0, 0, 0};
#pragma unroll
        for (int ks = 0; ks < 16; ++ks) {
            bf16x8 bh0 = *(const bf16x8*)(p0 + ks * 32);
            bf16x8 bl0 = *(const bf16x8*)(p0L + ks * 32);
            bf16x8 bh1 = *(const bf16x8*)(p1 + ks * 32);
            bf16x8 bl1 = *(const bf16x8*)(p1L + ks * 32);
            acc0a = __builtin_amdgcn_mfma_f32_16x16x32_bf16(aH[ks], bh0, acc0a, 0, 0, 0);
            acc0b = __builtin_amdgcn_mfma_f32_16x16x32_bf16(aH[ks], bl0, acc0b, 0, 0, 0);
            acc0c = __builtin_amdgcn_mfma_f32_16x16x32_bf16(aL[ks], bh0, acc0c, 0, 0, 0);
            acc1a = __builtin_amdgcn_mfma_f32_16x16x32_bf16(aH[ks], bh1, acc1a, 0, 0, 0);
            acc1b = __builtin_amdgcn_mfma_f32_16x16x32_bf16(aH[ks], bl1, acc1b, 0, 0, 0);
            acc1c = __builtin_amdgcn_mfma_f32_16x16x32_bf16(aL[ks], bh1, acc1c, 0, 0, 0);
        }
        f32x4 s0 = acc0a + acc0b + acc0c;
        f32x4 s1 = acc1a + acc1b + acc1c;
        // C layout: n = lane&15, m = (lane>>4)*4 + r
#pragma unroll
        for (int r = 0; r < 4; ++r) {
            int wo = mt * 16 + kg * 4 + r;
            if (wo < WW) {
                int dw0 = xo0 - wo + RR;
                if ((unsigned)dw0 < (unsigned)PD) corr[wo * CSTRIDE + dh * PD + dw0] = s0[r];
                int dw1 = xo1 - wo + RR;
                if (xo1 < WW && (unsigned)dw1 < (unsigned)PD)
                    corr[wo * CSTRIDE + dh * PD + dw1] = s1[r];
            }
        }
    }
    __syncthreads();

    // per-pixel softmax stats over 625 offsets (zeros present for OOB offsets)
    for (int w = wid; w < WW; w += 4) {
        float m = 0.f;
        for (int i = lane; i < PP; i += 64) m = fmaxf(m, corr[w * CSTRIDE + i]);
        m = fmaxf(m, __shfl_xor(m, 1));
        m = fmaxf(m, __shfl_xor(m, 2));
        m = fmaxf(m, __shfl_xor(m, 4));
        m = fmaxf(m, __shfl_xor(m, 8));
        m = fmaxf(m, __shfl_xor(m, 16));
        m = fmaxf(m, __shfl_xor(m, 32));
        float s = 0.f;
        for (int i = lane; i < PP; i += 64) {
            float e = __expf(512.f * (corr[w * CSTRIDE + i] - m));
            s += e;
            corr[w * CSTRIDE + i] = e;  // cache exp for write phase
        }
        s += __shfl_xor(s, 1);
        s += __shfl_xor(s, 2);
        s += __shfl_xor(s, 4);
        s += __shfl_xor(s, 8);
        s += __shfl_xor(s, 16);
        s += __shfl_xor(s, 32);
        if (lane == 0) is_lds[w] = 1.0f / s;
    }
    __syncthreads();

    // masked write: out[bt][i=dh*25+dw][h][w]
    float* obase = out + (long)bt * PP * HWD + h * WW;
    for (int idx = tid; idx < PP * WW; idx += 256) {
        int i = idx / 30;
        int w = idx - i * 30;
        int dh = i / 25, dw = i - dh * 25;
        bool valid = ((unsigned)(h + dh - RR) < (unsigned)HH) &&
                     ((unsigned)(w + dw - RR) < (unsigned)WW);
        float val = -1.0f;
        if (valid) val = corr[w * CSTRIDE + i] * is_lds[w];
        obase[(long)i * HWD + w] = val;
    }
}

extern "C" void kernel_launch(void* const* d_in, const int* in_sizes, int n_in,
                              void* d_out, int out_size, void* d_ws, size_t ws_size,
                              hipStream_t stream) {
    const float* feat1 = (const float*)d_in[0];  // video [8,512,4,30,30]
    const float* feat2 = (const float*)d_in[1];  // patch [8,512,30,30]
    float* out = (float*)d_out;
    unsigned short* Qh = (unsigned short*)d_ws;            // [8][900][512]
    unsigned short* Ql = Qh + (size_t)BD * HWD * CD;
    unsigned short* Vh = Ql + (size_t)BD * HWD * CD;       // [32][900][512]
    unsigned short* Vl = Vh + (size_t)(BD * TD) * HWD * CD;

    norm_kernel<<<dim3(29, 8), 256, 0, stream>>>(feat2, Qh, Ql, HWD, 1);
    norm_kernel<<<dim3(29, 32), 256, 0, stream>>>(feat1, Vh, Vl, TD * HWD, TD);
    corr_kernel<<<dim3(30, 32), 256, 0, stream>>>(Qh, Ql, Vh, Vl, out);
}

// Round 3
// 240.351 us; speedup vs baseline: 4.9082x; 1.8631x over previous
//
#include <hip/hip_runtime.h>

#define RR 12
#define PD 25
#define PP 625
#define HH 30
#define WW 30
#define HWD 900
#define CD 512
#define BD 8
#define TD 4
#define CSTRIDE 628           // 625 + 3 pad
#define ROWPK 32768           // shorts per packed (plane,row): 32ks * 2hl * 64lane * 8

typedef __attribute__((ext_vector_type(8))) short bf16x8;
typedef __attribute__((ext_vector_type(16))) float f32x16;

__device__ __forceinline__ unsigned short f2bf_rn(float x) {
    unsigned int u = __float_as_uint(x);
    u += 0x7fffu + ((u >> 16) & 1u);
    return (unsigned short)(u >> 16);
}

// relu + L2-normalize over C, then write hi/lo split-bf16 directly in
// 32x32x16-MFMA fragment-major layout: [plane][row][ks][hl][lane][8]
// element (pix x = lane&31, k = ks*16 + (lane>>5)*8 + j)
__global__ __launch_bounds__(256) void norm_pack_kernel(const float* __restrict__ in,
                                                        unsigned short* __restrict__ outp,
                                                        int c_stride, int t_count) {
    int row = blockIdx.x;    // y (or h), 0..29
    int plane = blockIdx.y;
    int b = plane / t_count;
    int t = plane - b * t_count;
    size_t base = (size_t)b * CD * c_stride + (size_t)t * HWD + row * WW;
    __shared__ float tile[30][516];
    __shared__ float inv[30];
    int tid = threadIdx.x;
    for (int it = 0; it < 64; ++it) {
        int lin = it * 256 + tid;
        int c = lin >> 5, p = lin & 31;
        if (p < 30) tile[p][c] = fmaxf(in[base + (size_t)c * c_stride + p], 0.f);
    }
    __syncthreads();
    if ((tid >> 3) < 30) {
        int p = tid >> 3, s8 = tid & 7;
        float acc = 0.f;
#pragma unroll
        for (int j = 0; j < 16; ++j) {
            const float4 v = *reinterpret_cast<const float4*>(&tile[p][(s8 + j * 8) * 4]);
            acc += v.x * v.x + v.y * v.y + v.z * v.z + v.w * v.w;
        }
        acc += __shfl_xor(acc, 1);
        acc += __shfl_xor(acc, 2);
        acc += __shfl_xor(acc, 4);
        if (s8 == 0) inv[p] = 1.0f / fmaxf(sqrtf(acc), 1e-12f);
    }
    __syncthreads();
    unsigned short* ob = outp + (size_t)(plane * 30 + row) * ROWPK;
    for (int sl = tid; sl < 2048; sl += 256) {   // sl = ks*64 + lane
        int ks = sl >> 6, ln = sl & 63;
        int x = ln & 31;
        if (x > 29) x = 29;                       // pad lanes (guarded in corr)
        int kb = ks * 16 + (ln >> 5) * 8;
        float iv = inv[x];
        bf16x8 hv, lv;
#pragma unroll
        for (int j = 0; j < 8; ++j) {
            float nv = tile[x][kb + j] * iv;
            unsigned short hs = f2bf_rn(nv);
            float hf = __uint_as_float((unsigned int)hs << 16);
            hv[j] = (short)hs;
            lv[j] = (short)f2bf_rn(nv - hf);
        }
        *(bf16x8*)(ob + (size_t)(ks * 2 + 0) * 512 + ln * 8) = hv;
        *(bf16x8*)(ob + (size_t)(ks * 2 + 1) * 512 + ln * 8) = lv;
    }
}

// block (h, bt), 512 thr = 8 waves; each wave owns dh slots (stride 8).
// One 32x32x16 MFMA tile covers all (w,x) per dh; 3-chain split-bf16.
__global__ __launch_bounds__(512, 4) void corr_kernel(
    const unsigned short* __restrict__ Apk, const unsigned short* __restrict__ Bpk,
    float* __restrict__ out) {
    int h = blockIdx.x;   // 0..29
    int bt = blockIdx.y;  // 0..31
    int b = bt >> 2;
    __shared__ float corr[HH * CSTRIDE];
    __shared__ float is_lds[HH];
    int tid = threadIdx.x;
    int wid = tid >> 6, lane = tid & 63;

    for (int i = tid; i < HH * CSTRIDE; i += 512) corr[i] = 0.f;

    const unsigned short* abase = Apk + (size_t)(b * 30 + h) * ROWPK + lane * 8;
    const unsigned short* bplane = Bpk + (size_t)bt * 30 * ROWPK + lane * 8;
    int dh_lo = max(0, RR - h);
    int dh_hi = min(PD - 1, HH - 1 + RR - h);
    __syncthreads();  // corr zeroed

    for (int dh = dh_lo + wid; dh <= dh_hi; dh += 8) {
        int y = h + dh - RR;
        const unsigned short* bbase = bplane + (size_t)y * ROWPK;
        f32x16 accA, accB, accC;
#pragma unroll
        for (int i = 0; i < 16; ++i) { accA[i] = 0.f; accB[i] = 0.f; accC[i] = 0.f; }
#pragma unroll 4
        for (int ks = 0; ks < 32; ++ks) {
            bf16x8 aH = *(const bf16x8*)(abase + ks * 1024);
            bf16x8 aL = *(const bf16x8*)(abase + ks * 1024 + 512);
            bf16x8 bH = *(const bf16x8*)(bbase + ks * 1024);
            bf16x8 bL = *(const bf16x8*)(bbase + ks * 1024 + 512);
            accA = __builtin_amdgcn_mfma_f32_32x32x16_bf16(aH, bH, accA, 0, 0, 0);
            accB = __builtin_amdgcn_mfma_f32_32x32x16_bf16(aH, bL, accB, 0, 0, 0);
            accC = __builtin_amdgcn_mfma_f32_32x32x16_bf16(aL, bH, accC, 0, 0, 0);
        }
        int x = lane & 31;
        if (x < 30) {
            int rbase = 4 * (lane >> 5);
#pragma unroll
            for (int r = 0; r < 16; ++r) {
                int w = (r & 3) + 8 * (r >> 2) + rbase;  // C layout: col=lane&31, row formula
                int dw = x - w + RR;
                if (w < 30 && (unsigned)dw < (unsigned)PD)
                    corr[w * CSTRIDE + dh * PD + dw] = accA[r] + accB[r] + accC[r];
            }
        }
    }
    __syncthreads();

    // per-pixel softmax over 625 offsets (zeros present for OOB offsets)
    for (int w = wid; w < WW; w += 8) {
        float m = 0.f;
        for (int i = lane; i < PP; i += 64) m = fmaxf(m, corr[w * CSTRIDE + i]);
        m = fmaxf(m, __shfl_xor(m, 1));
        m = fmaxf(m, __shfl_xor(m, 2));
        m = fmaxf(m, __shfl_xor(m, 4));
        m = fmaxf(m, __shfl_xor(m, 8));
        m = fmaxf(m, __shfl_xor(m, 16));
        m = fmaxf(m, __shfl_xor(m, 32));
        float s = 0.f;
        for (int i = lane; i < PP; i += 64) {
            float e = __expf(512.f * (corr[w * CSTRIDE + i] - m));
            s += e;
            corr[w * CSTRIDE + i] = e;  // cache exp for write phase
        }
        s += __shfl_xor(s, 1);
        s += __shfl_xor(s, 2);
        s += __shfl_xor(s, 4);
        s += __shfl_xor(s, 8);
        s += __shfl_xor(s, 16);
        s += __shfl_xor(s, 32);
        if (lane == 0) is_lds[w] = 1.0f / s;
    }
    __syncthreads();

    // masked write: out[bt][i=dh*25+dw][h][w]
    float* obase = out + (size_t)bt * PP * HWD + h * WW;
    for (int idx = tid; idx < PP * WW; idx += 512) {
        int i = idx / 30;
        int w = idx - i * 30;
        int dh = i / 25, dw = i - dh * 25;
        bool valid = ((unsigned)(h + dh - RR) < (unsigned)HH) &&
                     ((unsigned)(w + dw - RR) < (unsigned)WW);
        float val = -1.0f;
        if (valid) val = corr[w * CSTRIDE + i] * is_lds[w];
        obase[(size_t)i * HWD + w] = val;
    }
}

extern "C" void kernel_launch(void* const* d_in, const int* in_sizes, int n_in,
                              void* d_out, int out_size, void* d_ws, size_t ws_size,
                              hipStream_t stream) {
    const float* feat1 = (const float*)d_in[0];  // video [8,512,4,30,30]
    const float* feat2 = (const float*)d_in[1];  // patch [8,512,30,30]
    float* out = (float*)d_out;
    unsigned short* Apk = (unsigned short*)d_ws;                 // [8*30][ROWPK]
    unsigned short* Bpk = Apk + (size_t)BD * 30 * ROWPK;         // [32*30][ROWPK]

    norm_pack_kernel<<<dim3(30, 8), 256, 0, stream>>>(feat2, Apk, HWD, 1);
    norm_pack_kernel<<<dim3(30, 32), 256, 0, stream>>>(feat1, Bpk, TD * HWD, TD);
    corr_kernel<<<dim3(30, 32), 512, 0, stream>>>(Apk, Bpk, out);
}

// Round 4
// 179.360 us; speedup vs baseline: 6.5773x; 1.3400x over previous
//
#include <hip/hip_runtime.h>

#define RR 12
#define PD 25
#define PP 625
#define HH 30
#define WW 30
#define HWD 900
#define CD 512
#define BD 8
#define TD 4
#define CSTRIDE 628           // 625 + 3 pad
#define ROWPK 32768           // shorts per packed (plane,row): 32ks * 2hl * 64lane * 8

typedef __attribute__((ext_vector_type(8))) short bf16x8;
typedef __attribute__((ext_vector_type(16))) float f32x16;

__device__ __forceinline__ unsigned short f2bf_rn(float x) {
    unsigned int u = __float_as_uint(x);
    u += 0x7fffu + ((u >> 16) & 1u);
    return (unsigned short)(u >> 16);
}

// relu + L2-normalize over C, then write hi/lo split-bf16 directly in
// 32x32x16-MFMA fragment-major layout: [plane][row][ks][hl][lane][8]
// element (pix x = lane&31, k = ks*16 + (lane>>5)*8 + j)
__global__ __launch_bounds__(256) void norm_pack_kernel(const float* __restrict__ in,
                                                        unsigned short* __restrict__ outp,
                                                        int c_stride, int t_count) {
    int row = blockIdx.x;    // y (or h), 0..29
    int plane = blockIdx.y;
    int b = plane / t_count;
    int t = plane - b * t_count;
    size_t base = (size_t)b * CD * c_stride + (size_t)t * HWD + row * WW;
    __shared__ float tile[30][516];
    __shared__ float inv[30];
    int tid = threadIdx.x;
    for (int it = 0; it < 64; ++it) {
        int lin = it * 256 + tid;
        int c = lin >> 5, p = lin & 31;
        if (p < 30) tile[p][c] = fmaxf(in[base + (size_t)c * c_stride + p], 0.f);
    }
    __syncthreads();
    if ((tid >> 3) < 30) {
        int p = tid >> 3, s8 = tid & 7;
        float acc = 0.f;
#pragma unroll
        for (int j = 0; j < 16; ++j) {
            const float4 v = *reinterpret_cast<const float4*>(&tile[p][(s8 + j * 8) * 4]);
            acc += v.x * v.x + v.y * v.y + v.z * v.z + v.w * v.w;
        }
        acc += __shfl_xor(acc, 1);
        acc += __shfl_xor(acc, 2);
        acc += __shfl_xor(acc, 4);
        if (s8 == 0) inv[p] = 1.0f / fmaxf(sqrtf(acc), 1e-12f);
    }
    __syncthreads();
    unsigned short* ob = outp + (size_t)(plane * 30 + row) * ROWPK;
    for (int sl = tid; sl < 2048; sl += 256) {   // sl = ks*64 + lane
        int ks = sl >> 6, ln = sl & 63;
        int x = ln & 31;
        if (x > 29) x = 29;                       // pad lanes (guarded in corr)
        int kb = ks * 16 + (ln >> 5) * 8;
        float iv = inv[x];
        bf16x8 hv, lv;
#pragma unroll
        for (int j = 0; j < 8; ++j) {
            float nv = tile[x][kb + j] * iv;
            unsigned short hs = f2bf_rn(nv);
            float hf = __uint_as_float((unsigned int)hs << 16);
            hv[j] = (short)hs;
            lv[j] = (short)f2bf_rn(nv - hf);
        }
        *(bf16x8*)(ob + (size_t)(ks * 2 + 0) * 512 + ln * 8) = hv;
        *(bf16x8*)(ob + (size_t)(ks * 2 + 1) * 512 + ln * 8) = lv;
    }
}

// 1D grid of 960, XCD-bijective swizzle: xcd r owns b=r (bt in 4r..4r+3, h-major).
// 512 thr = 8 waves; wave owns dh slots (stride 8). A-row staged in LDS once;
// one 32x32x16 MFMA tile covers all (w,x) per dh; 3-chain split-bf16.
__global__ __launch_bounds__(512, 2) void corr_kernel(
    const unsigned short* __restrict__ Apk, const unsigned short* __restrict__ Bpk,
    float* __restrict__ out) {
    int gid = blockIdx.x;
    int r = gid & 7;          // target XCD
    int x_ = gid >> 3;        // 0..119
    int btl = x_ / 30;
    int h = x_ - btl * 30;
    int bt = r * 4 + btl;
    int b = r;

    __shared__ float corr[HH * CSTRIDE];
    __shared__ unsigned short alds[ROWPK];
    __shared__ float is_lds[HH];
    int tid = threadIdx.x;
    int wid = tid >> 6, lane = tid & 63;

    for (int i = tid; i < HH * CSTRIDE; i += 512) corr[i] = 0.f;
    // stage A row (64 KB) into LDS, linear copy
    {
        const uint4* src = (const uint4*)(Apk + (size_t)(b * 30 + h) * ROWPK);
        uint4* dst = (uint4*)alds;
#pragma unroll
        for (int i = 0; i < 8; ++i) dst[i * 512 + tid] = src[i * 512 + tid];
    }
    const unsigned short* bplane = Bpk + (size_t)bt * 30 * ROWPK + lane * 8;
    int dh_lo = max(0, RR - h);
    int dh_hi = min(PD - 1, HH - 1 + RR - h);
    __syncthreads();  // corr zeroed + A staged

    const unsigned short* albase = alds + lane * 8;
    for (int dh = dh_lo + wid; dh <= dh_hi; dh += 8) {
        int y = h + dh - RR;
        const unsigned short* bbase = bplane + (size_t)y * ROWPK;
        f32x16 accA, accB, accC;
#pragma unroll
        for (int i = 0; i < 16; ++i) { accA[i] = 0.f; accB[i] = 0.f; accC[i] = 0.f; }
#pragma unroll 8
        for (int ks = 0; ks < 32; ++ks) {
            bf16x8 aH = *(const bf16x8*)(albase + ks * 1024);
            bf16x8 aL = *(const bf16x8*)(albase + ks * 1024 + 512);
            bf16x8 bH = *(const bf16x8*)(bbase + ks * 1024);
            bf16x8 bL = *(const bf16x8*)(bbase + ks * 1024 + 512);
            accA = __builtin_amdgcn_mfma_f32_32x32x16_bf16(aH, bH, accA, 0, 0, 0);
            accB = __builtin_amdgcn_mfma_f32_32x32x16_bf16(aH, bL, accB, 0, 0, 0);
            accC = __builtin_amdgcn_mfma_f32_32x32x16_bf16(aL, bH, accC, 0, 0, 0);
        }
        int x = lane & 31;
        if (x < 30) {
            int rbase = 4 * (lane >> 5);
#pragma unroll
            for (int rr = 0; rr < 16; ++rr) {
                int w = (rr & 3) + 8 * (rr >> 2) + rbase;  // C layout: col=lane&31
                int dw = x - w + RR;
                if (w < 30 && (unsigned)dw < (unsigned)PD)
                    corr[w * CSTRIDE + dh * PD + dw] = accA[rr] + accB[rr] + accC[rr];
            }
        }
    }
    __syncthreads();

    // per-pixel softmax over 625 offsets (zeros present for OOB offsets)
    for (int w = wid; w < WW; w += 8) {
        float m = 0.f;
        for (int i = lane; i < PP; i += 64) m = fmaxf(m, corr[w * CSTRIDE + i]);
        m = fmaxf(m, __shfl_xor(m, 1));
        m = fmaxf(m, __shfl_xor(m, 2));
        m = fmaxf(m, __shfl_xor(m, 4));
        m = fmaxf(m, __shfl_xor(m, 8));
        m = fmaxf(m, __shfl_xor(m, 16));
        m = fmaxf(m, __shfl_xor(m, 32));
        float s = 0.f;
        for (int i = lane; i < PP; i += 64) {
            float e = __expf(512.f * (corr[w * CSTRIDE + i] - m));
            s += e;
            corr[w * CSTRIDE + i] = e;  // cache exp for write phase
        }
        s += __shfl_xor(s, 1);
        s += __shfl_xor(s, 2);
        s += __shfl_xor(s, 4);
        s += __shfl_xor(s, 8);
        s += __shfl_xor(s, 16);
        s += __shfl_xor(s, 32);
        if (lane == 0) is_lds[w] = 1.0f / s;
    }
    __syncthreads();

    // masked write: out[bt][i=dh*25+dw][h][w]
    float* obase = out + (size_t)bt * PP * HWD + h * WW;
    for (int idx = tid; idx < PP * WW; idx += 512) {
        int i = idx / 30;
        int w = idx - i * 30;
        int dh = i / 25, dw = i - dh * 25;
        bool valid = ((unsigned)(h + dh - RR) < (unsigned)HH) &&
                     ((unsigned)(w + dw - RR) < (unsigned)WW);
        float val = -1.0f;
        if (valid) val = corr[w * CSTRIDE + i] * is_lds[w];
        obase[(size_t)i * HWD + w] = val;
    }
}

extern "C" void kernel_launch(void* const* d_in, const int* in_sizes, int n_in,
                              void* d_out, int out_size, void* d_ws, size_t ws_size,
                              hipStream_t stream) {
    const float* feat1 = (const float*)d_in[0];  // video [8,512,4,30,30]
    const float* feat2 = (const float*)d_in[1];  // patch [8,512,30,30]
    float* out = (float*)d_out;
    unsigned short* Apk = (unsigned short*)d_ws;                 // [8*30][ROWPK]
    unsigned short* Bpk = Apk + (size_t)BD * 30 * ROWPK;         // [32*30][ROWPK]

    norm_pack_kernel<<<dim3(30, 8), 256, 0, stream>>>(feat2, Apk, HWD, 1);
    norm_pack_kernel<<<dim3(30, 32), 256, 0, stream>>>(feat1, Bpk, TD * HWD, TD);
    corr_kernel<<<dim3(960), 512, 0, stream>>>(Apk, Bpk, out);
}

// Round 5
// 146.946 us; speedup vs baseline: 8.0281x; 1.2206x over previous
//
#include <hip/hip_runtime.h>

#define RR 12
#define PD 25
#define PP 625
#define HH 30
#define WW 30
#define HWD 900
#define CD 512
#define BD 8
#define TD 4
#define CSTRIDE 628           // 625 + 3 pad
#define ROWPK 32768           // shorts per packed (plane,row): 32ks * 2hl * 64lane * 8

typedef __attribute__((ext_vector_type(8))) short bf16x8;
typedef __attribute__((ext_vector_type(16))) float f32x16;

__device__ __forceinline__ unsigned short f2bf_rn(float x) {
    unsigned int u = __float_as_uint(x);
    u += 0x7fffu + ((u >> 16) & 1u);
    return (unsigned short)(u >> 16);
}

// relu + L2-normalize over C, then write hi/lo split-bf16 directly in
// 32x32x16-MFMA fragment-major layout: [plane][row][ks][hl][lane][8]
// element (pix x = lane&31, k = ks*16 + (lane>>5)*8 + j)
__global__ __launch_bounds__(256) void norm_pack_kernel(const float* __restrict__ in,
                                                        unsigned short* __restrict__ outp,
                                                        int c_stride, int t_count) {
    int row = blockIdx.x;    // y (or h), 0..29
    int plane = blockIdx.y;
    int b = plane / t_count;
    int t = plane - b * t_count;
    size_t base = (size_t)b * CD * c_stride + (size_t)t * HWD + row * WW;
    __shared__ float tile[30][516];
    __shared__ float inv[30];
    int tid = threadIdx.x;
    for (int it = 0; it < 64; ++it) {
        int lin = it * 256 + tid;
        int c = lin >> 5, p = lin & 31;
        if (p < 30) tile[p][c] = fmaxf(in[base + (size_t)c * c_stride + p], 0.f);
    }
    __syncthreads();
    if ((tid >> 3) < 30) {
        int p = tid >> 3, s8 = tid & 7;
        float acc = 0.f;
#pragma unroll
        for (int j = 0; j < 16; ++j) {
            const float4 v = *reinterpret_cast<const float4*>(&tile[p][(s8 + j * 8) * 4]);
            acc += v.x * v.x + v.y * v.y + v.z * v.z + v.w * v.w;
        }
        acc += __shfl_xor(acc, 1);
        acc += __shfl_xor(acc, 2);
        acc += __shfl_xor(acc, 4);
        if (s8 == 0) inv[p] = 1.0f / fmaxf(sqrtf(acc), 1e-12f);
    }
    __syncthreads();
    unsigned short* ob = outp + (size_t)(plane * 30 + row) * ROWPK;
    for (int sl = tid; sl < 2048; sl += 256) {   // sl = ks*64 + lane
        int ks = sl >> 6, ln = sl & 63;
        int x = ln & 31;
        if (x > 29) x = 29;                       // pad lanes (guarded in corr)
        int kb = ks * 16 + (ln >> 5) * 8;
        float iv = inv[x];
        bf16x8 hv, lv;
#pragma unroll
        for (int j = 0; j < 8; ++j) {
            float nv = tile[x][kb + j] * iv;
            unsigned short hs = f2bf_rn(nv);
            float hf = __uint_as_float((unsigned int)hs << 16);
            hv[j] = (short)hs;
            lv[j] = (short)f2bf_rn(nv - hf);
        }
        *(bf16x8*)(ob + (size_t)(ks * 2 + 0) * 512 + ln * 8) = hv;
        *(bf16x8*)(ob + (size_t)(ks * 2 + 1) * 512 + ln * 8) = lv;
    }
}

// 1D grid of 960, XCD-bijective swizzle: xcd r owns b=r (bt in 4r..4r+3, h-major).
// 1024 thr = 16 waves (4/SIMD); wave owns dh slots (stride 16). A-row staged in
// LDS once; one 32x32x16 MFMA tile covers all (w,x) per dh; 3-chain split-bf16.
__global__ __launch_bounds__(1024, 4) void corr_kernel(
    const unsigned short* __restrict__ Apk, const unsigned short* __restrict__ Bpk,
    float* __restrict__ out) {
    int gid = blockIdx.x;
    int r = gid & 7;          // target XCD
    int x_ = gid >> 3;        // 0..119
    int btl = x_ / 30;
    int h = x_ - btl * 30;
    int bt = r * 4 + btl;
    int b = r;

    __shared__ float corr[HH * CSTRIDE];
    __shared__ unsigned short alds[ROWPK];
    __shared__ float is_lds[HH];
    int tid = threadIdx.x;
    int wid = tid >> 6, lane = tid & 63;

    for (int i = tid; i < HH * CSTRIDE; i += 1024) corr[i] = 0.f;
    // stage A row (64 KB) into LDS, linear copy
    {
        const uint4* src = (const uint4*)(Apk + (size_t)(b * 30 + h) * ROWPK);
        uint4* dst = (uint4*)alds;
#pragma unroll
        for (int i = 0; i < 4; ++i) dst[i * 1024 + tid] = src[i * 1024 + tid];
    }
    const unsigned short* bplane = Bpk + (size_t)bt * 30 * ROWPK + lane * 8;
    int dh_lo = max(0, RR - h);
    int dh_hi = min(PD - 1, HH - 1 + RR - h);
    __syncthreads();  // corr zeroed + A staged

    const unsigned short* albase = alds + lane * 8;
    for (int dh = dh_lo + wid; dh <= dh_hi; dh += 16) {
        int y = h + dh - RR;
        const unsigned short* bbase = bplane + (size_t)y * ROWPK;
        f32x16 accA, accB, accC;
#pragma unroll
        for (int i = 0; i < 16; ++i) { accA[i] = 0.f; accB[i] = 0.f; accC[i] = 0.f; }
#pragma unroll 8
        for (int ks = 0; ks < 32; ++ks) {
            bf16x8 aH = *(const bf16x8*)(albase + ks * 1024);
            bf16x8 aL = *(const bf16x8*)(albase + ks * 1024 + 512);
            bf16x8 bH = *(const bf16x8*)(bbase + ks * 1024);
            bf16x8 bL = *(const bf16x8*)(bbase + ks * 1024 + 512);
            accA = __builtin_amdgcn_mfma_f32_32x32x16_bf16(aH, bH, accA, 0, 0, 0);
            accB = __builtin_amdgcn_mfma_f32_32x32x16_bf16(aH, bL, accB, 0, 0, 0);
            accC = __builtin_amdgcn_mfma_f32_32x32x16_bf16(aL, bH, accC, 0, 0, 0);
        }
        int x = lane & 31;
        if (x < 30) {
            int rbase = 4 * (lane >> 5);
#pragma unroll
            for (int rr = 0; rr < 16; ++rr) {
                int w = (rr & 3) + 8 * (rr >> 2) + rbase;  // C layout: col=lane&31
                int dw = x - w + RR;
                if (w < 30 && (unsigned)dw < (unsigned)PD)
                    corr[w * CSTRIDE + dh * PD + dw] = accA[rr] + accB[rr] + accC[rr];
            }
        }
    }
    __syncthreads();

    // per-pixel softmax over 625 offsets (zeros present for OOB offsets)
    for (int w = wid; w < WW; w += 16) {
        float m = 0.f;
        for (int i = lane; i < PP; i += 64) m = fmaxf(m, corr[w * CSTRIDE + i]);
        m = fmaxf(m, __shfl_xor(m, 1));
        m = fmaxf(m, __shfl_xor(m, 2));
        m = fmaxf(m, __shfl_xor(m, 4));
        m = fmaxf(m, __shfl_xor(m, 8));
        m = fmaxf(m, __shfl_xor(m, 16));
        m = fmaxf(m, __shfl_xor(m, 32));
        float s = 0.f;
        for (int i = lane; i < PP; i += 64) {
            float e = __expf(512.f * (corr[w * CSTRIDE + i] - m));
            s += e;
            corr[w * CSTRIDE + i] = e;  // cache exp for write phase
        }
        s += __shfl_xor(s, 1);
        s += __shfl_xor(s, 2);
        s += __shfl_xor(s, 4);
        s += __shfl_xor(s, 8);
        s += __shfl_xor(s, 16);
        s += __shfl_xor(s, 32);
        if (lane == 0) is_lds[w] = 1.0f / s;
    }
    __syncthreads();

    // masked write: out[bt][i=dh*25+dw][h][w]
    float* obase = out + (size_t)bt * PP * HWD + h * WW;
    for (int idx = tid; idx < PP * WW; idx += 1024) {
        int i = idx / 30;
        int w = idx - i * 30;
        int dh = i / 25, dw = i - dh * 25;
        bool valid = ((unsigned)(h + dh - RR) < (unsigned)HH) &&
                     ((unsigned)(w + dw - RR) < (unsigned)WW);
        float val = -1.0f;
        if (valid) val = corr[w * CSTRIDE + i] * is_lds[w];
        obase[(size_t)i * HWD + w] = val;
    }
}

extern "C" void kernel_launch(void* const* d_in, const int* in_sizes, int n_in,
                              void* d_out, int out_size, void* d_ws, size_t ws_size,
                              hipStream_t stream) {
    const float* feat1 = (const float*)d_in[0];  // video [8,512,4,30,30]
    const float* feat2 = (const float*)d_in[1];  // patch [8,512,30,30]
    float* out = (float*)d_out;
    unsigned short* Apk = (unsigned short*)d_ws;                 // [8*30][ROWPK]
    unsigned short* Bpk = Apk + (size_t)BD * 30 * ROWPK;         // [32*30][ROWPK]

    norm_pack_kernel<<<dim3(30, 8), 256, 0, stream>>>(feat2, Apk, HWD, 1);
    norm_pack_kernel<<<dim3(30, 32), 256, 0, stream>>>(feat1, Bpk, TD * HWD, TD);
    corr_kernel<<<dim3(960), 1024, 0, stream>>>(Apk, Bpk, out);
}